// Round 1
// baseline (1421.607 us; speedup 1.0000x reference)
//
#include <hip/hip_runtime.h>
#include <stdint.h>

// Row length is fixed by the reference: features [1024, 12, 16384] fp32.
#define ROW_D   16384
#define BLOCK   256
#define F4PT    (ROW_D / 4 / BLOCK)   // 16 float4 per thread (64 elements)
#define LIST_CAP 1024
#define SLOTS   (LIST_CAP / BLOCK)    // 4 candidate slots per thread

// Order-preserving float->uint32 key map (monotonic; total order, -0 < +0).
__device__ __forceinline__ uint32_t f2k(float f) {
    uint32_t u = __float_as_uint(f);
    return u ^ ((uint32_t)((int32_t)u >> 31) | 0x80000000u);
}

__device__ __forceinline__ int waveReduce(int c) {
#pragma unroll
    for (int off = 32; off > 0; off >>= 1) c += __shfl_down(c, off, 64);
    return c;
}

__global__ __launch_bounds__(BLOCK, 2)
void PerLayerTopK_kernel(const float* __restrict__ in, const int* __restrict__ kptr,
                         float* __restrict__ out) {
    __shared__ uint32_t s_list[LIST_CAP];
    __shared__ int s_listCnt;
    __shared__ int s_red;
    __shared__ uint32_t s_thrKey;
    __shared__ int s_cntGt;
    __shared__ int s_cntEq;

    const int t    = threadIdx.x;
    const int lane = t & 63;
    const int row  = blockIdx.x;
    const int k    = *kptr;

    const float4* __restrict__ src = (const float4*)(in  + (size_t)row * ROW_D);
    float4* __restrict__       dst = (float4*)(out + (size_t)row * ROW_D);

    if (t == 0) s_listCnt = 0;
    __syncthreads();

    // ---- Phase 1: row -> registers (coalesced float4 burst, 16 outstanding) ----
    float4 vv[F4PT];
#pragma unroll
    for (int j = 0; j < F4PT; ++j) vv[j] = src[t + j * BLOCK];

    // ---- Phase 2: compact keys > pivot into small LDS list (ballot-aggregated) ----
    const uint32_t kpiv = f2k(2.3f);   // ~8 sigma below the 64th order statistic of N(0,1)
#pragma unroll
    for (int j = 0; j < F4PT; ++j) {
#pragma unroll
        for (int c = 0; c < 4; ++c) {
            float x = (c == 0) ? vv[j].x : (c == 1) ? vv[j].y : (c == 2) ? vv[j].z : vv[j].w;
            uint32_t key = f2k(x);
            bool pred = key > kpiv;
            unsigned long long m = __ballot(pred ? 1 : 0);
            if (m != 0ull) {
                int leader = __ffsll(m) - 1;
                int base = 0;
                if (lane == leader) base = atomicAdd(&s_listCnt, __popcll(m));
                base = __shfl(base, leader, 64);
                if (pred) {
                    int slot = base + __popcll(m & ((1ull << lane) - 1ull));
                    if (slot < LIST_CAP) s_list[slot] = key;
                }
            }
        }
    }
    __syncthreads();

    const int n = s_listCnt;
    const bool fast = (n >= k) && (n <= LIST_CAP);   // block-uniform

    if (fast) {
        // ---- Phase 3a: exact rank-(k-1) selection within the small list ----
        // All elements > pivot are in the list, so within-list gt/eq counts are global.
        uint32_t e[SLOTS]; int gt[SLOTS]; int eq[SLOTS];
#pragma unroll
        for (int s = 0; s < SLOTS; ++s) {
            int idx = t + s * BLOCK;
            e[s] = (idx < n) ? s_list[idx] : 0u;
            gt[s] = 0; eq[s] = 0;
        }
        for (int j = 0; j < n; ++j) {
            uint32_t kj = s_list[j];      // LDS broadcast read
#pragma unroll
            for (int s = 0; s < SLOTS; ++s) {
                gt[s] += (kj > e[s]) ? 1 : 0;
                eq[s] += (kj == e[s]) ? 1 : 0;
            }
        }
#pragma unroll
        for (int s = 0; s < SLOTS; ++s) {
            int idx = t + s * BLOCK;
            if (idx < n && gt[s] <= k - 1 && k - 1 < gt[s] + eq[s]) {
                // possibly multiple writers on duplicate keys -> identical values, benign
                s_thrKey = e[s]; s_cntGt = gt[s]; s_cntEq = eq[s];
            }
        }
    } else {
        // ---- Phase 3b (fallback, any-input-correct): 32-step radix bisection ----
        uint32_t lo = 0u;
        for (int b = 31; b >= 0; --b) {
            uint32_t mid = lo | (1u << b);
            if (t == 0) s_red = 0;
            __syncthreads();
            int c = 0;
#pragma unroll
            for (int j = 0; j < F4PT; ++j) {
                c += (f2k(vv[j].x) >= mid);
                c += (f2k(vv[j].y) >= mid);
                c += (f2k(vv[j].z) >= mid);
                c += (f2k(vv[j].w) >= mid);
            }
            c = waveReduce(c);
            if (lane == 0) atomicAdd(&s_red, c);
            __syncthreads();
            if (s_red >= k) lo = mid;   // keep largest key with count(>=key) >= k
            __syncthreads();
        }
        if (t == 0) { s_thrKey = lo; s_cntGt = 0; s_cntEq = 0; }
        __syncthreads();
        int cg = 0, ce = 0;
#pragma unroll
        for (int j = 0; j < F4PT; ++j) {
            uint32_t k0 = f2k(vv[j].x), k1 = f2k(vv[j].y), k2 = f2k(vv[j].z), k3 = f2k(vv[j].w);
            cg += (k0 > lo) + (k1 > lo) + (k2 > lo) + (k3 > lo);
            ce += (k0 == lo) + (k1 == lo) + (k2 == lo) + (k3 == lo);
        }
        cg = waveReduce(cg); ce = waveReduce(ce);
        if (lane == 0) { atomicAdd(&s_cntGt, cg); atomicAdd(&s_cntEq, ce); }
    }
    __syncthreads();

    const uint32_t thrKey = s_thrKey;
    const int cntGt = s_cntGt;
    const int cntEq = s_cntEq;
    const int numEqKeep = k - cntGt;   // in [1, cntEq]

    if (cntEq == numEqKeep) {
        // ---- Phase 4 common: keep everything >= threshold ----
#pragma unroll
        for (int j = 0; j < F4PT; ++j) {
            float4 v = vv[j];
            float4 o;
            o.x = (f2k(v.x) >= thrKey) ? v.x : 0.0f;
            o.y = (f2k(v.y) >= thrKey) ? v.y : 0.0f;
            o.z = (f2k(v.z) >= thrKey) ? v.z : 0.0f;
            o.w = (f2k(v.w) >= thrKey) ? v.w : 0.0f;
            dst[t + j * BLOCK] = o;
        }
    } else {
        // ---- Phase 4 rare: ties at threshold. top_k keeps LOWEST indices first.
        // Bisect the index cutoff: largest I0 with (#eq at idx < I0) < numEqKeep;
        // then keeping eq elements with idx <= I0 keeps exactly numEqKeep of them.
        int I0 = 0;
        for (int b = 13; b >= 0; --b) {    // 2^14 = 16384 = ROW_D
            int cand = I0 | (1 << b);
            if (t == 0) s_red = 0;
            __syncthreads();
            int c = 0;
#pragma unroll
            for (int j = 0; j < F4PT; ++j) {
                int bidx = 4 * (t + j * BLOCK);
                c += (f2k(vv[j].x) == thrKey && (bidx + 0) < cand);
                c += (f2k(vv[j].y) == thrKey && (bidx + 1) < cand);
                c += (f2k(vv[j].z) == thrKey && (bidx + 2) < cand);
                c += (f2k(vv[j].w) == thrKey && (bidx + 3) < cand);
            }
            c = waveReduce(c);
            if (lane == 0) atomicAdd(&s_red, c);
            __syncthreads();
            if (s_red < numEqKeep) I0 = cand;
            __syncthreads();
        }
#pragma unroll
        for (int j = 0; j < F4PT; ++j) {
            float4 v = vv[j];
            int bidx = 4 * (t + j * BLOCK);
            float4 o;
            uint32_t kk;
            kk = f2k(v.x); o.x = (kk > thrKey || (kk == thrKey && (bidx + 0) <= I0)) ? v.x : 0.0f;
            kk = f2k(v.y); o.y = (kk > thrKey || (kk == thrKey && (bidx + 1) <= I0)) ? v.y : 0.0f;
            kk = f2k(v.z); o.z = (kk > thrKey || (kk == thrKey && (bidx + 2) <= I0)) ? v.z : 0.0f;
            kk = f2k(v.w); o.w = (kk > thrKey || (kk == thrKey && (bidx + 3) <= I0)) ? v.w : 0.0f;
            dst[t + j * BLOCK] = o;
        }
    }
}

extern "C" void kernel_launch(void* const* d_in, const int* in_sizes, int n_in,
                              void* d_out, int out_size, void* d_ws, size_t ws_size,
                              hipStream_t stream) {
    const float* feat = (const float*)d_in[0];
    const int*   kp   = (const int*)d_in[1];
    float*       out  = (float*)d_out;
    const int nrows = in_sizes[0] / ROW_D;   // 1024*12 = 12288
    PerLayerTopK_kernel<<<nrows, BLOCK, 0, stream>>>(feat, kp, out);
}